// Round 7
// baseline (162.146 us; speedup 1.0000x reference)
//
#include <hip/hip_runtime.h>
#include <hip/hip_bf16.h>

#define NN 256
#define HH 256

typedef __attribute__((ext_vector_type(8))) short short8;
typedef __attribute__((ext_vector_type(4))) float f32x4;

__device__ __forceinline__ ushort f2bf(float x) {
    __hip_bfloat16 h = __float2bfloat16(x);
    return *reinterpret_cast<ushort*>(&h);
}
template <int CTRL>
__device__ __forceinline__ float dpp_add(float x) {
    int y = __builtin_amdgcn_update_dpp(0, __float_as_int(x), CTRL, 0xF, 0xF, true);
    return x + __int_as_float(y);
}
template <int CTRL>
__device__ __forceinline__ float dpp_max(float x) {
    int y = __builtin_amdgcn_update_dpp(0, __float_as_int(x), CTRL, 0xF, 0xF, true);
    return fmaxf(x, __int_as_float(y));
}
__device__ __forceinline__ float red16(float v) {      // sum within 16-lane row
    v = dpp_add<0xB1>(v); v = dpp_add<0x4E>(v);
    v = dpp_add<0x141>(v); v = dpp_add<0x140>(v);
    return v;
}
__device__ __forceinline__ float red16max(float v) {   // max within 16-lane row
    v = dpp_max<0xB1>(v); v = dpp_max<0x4E>(v);
    v = dpp_max<0x141>(v); v = dpp_max<0x140>(v);
    return v;
}

// Workspace layout (float offsets). Total 1,689,600 floats = 6,758,400 B.
#define WS_P   0         // P[256][64]
#define WS_Q   16384     // Q[256][64]
#define WS_T   32768     // T[256][256]
#define WS_WA  98304     // WA[4][256]
#define WS_WB  99328     // WB[4][256]
#define WS_WGT 100352    // WgT ushort[256][64]  (8192 floats — R6 under-reserved: bugfix)
#define WS_PV  108544    // PV[4][4][256][256]   unnormalized v partials
#define WS_ML  1157120   // ML[4][4][256][2]
#define WS_VNH 1165312   // VNhi ushort[256][1024]
#define WS_VNL 1296384   // VNlo ushort[256][1024]
#define WS_W2H 1427456   // W2hi ushort[256f][1024k]  (w transposed, bf16 hi)
#define WS_W2L 1558528   // W2lo ushort[256f][1024k]

// grid 464: [0,64) T tanh | [64,128) P/Q | [128,144) WA/WB | [144,208) WgT | [208,464) W2 split
__global__ __launch_bounds__(256) void precompute_kernel(
    const float* __restrict__ ahs, const float* __restrict__ goal,
    const float* __restrict__ action, const float* __restrict__ Wd,
    const float* __restrict__ b_dist, const float* __restrict__ Wg,
    const float* __restrict__ w, const float* __restrict__ a,
    float* __restrict__ ws)
{
    const int b = blockIdx.x;
    const int t = threadIdx.x;
    float* P  = ws + WS_P;
    float* Q  = ws + WS_Q;
    float* T  = ws + WS_T;
    float* WA = ws + WS_WA;
    float* WB = ws + WS_WB;
    ushort* WgT  = (ushort*)(ws + WS_WGT);
    ushort* W2hi = (ushort*)(ws + WS_W2H);
    ushort* W2lo = (ushort*)(ws + WS_W2L);

    if (b < 64) {
        const int idx = (b*256 + t)*4;
        float4 v = *(const float4*)(ahs + idx);
        float4 o;
        o.x = tanhf(v.x); o.y = tanhf(v.y); o.z = tanhf(v.z); o.w = tanhf(v.w);
        *(float4*)(T + idx) = o;
    } else if (b < 128) {
        const int i = (b - 64)*4 + (t >> 6);
        const int d = t & 63;
        float a0 = action[2*i], a1 = action[2*i+1];
        float g0 = goal[2*i],   g1 = goal[2*i+1];
        P[i*64 + d] = a0*Wd[0*64+d] + a1*Wd[1*64+d]
                    + g0*Wd[2*64+d] + g1*Wd[3*64+d] + b_dist[d];
        Q[i*64 + d] = a0*Wd[4*64+d] + a1*Wd[5*64+d]
                    + g0*Wd[6*64+d] + g1*Wd[7*64+d];
    } else if (b < 144) {
        const int r    = b - 128;
        const int z    = r >> 2;
        const int rg   = r & 3;
        const int wid  = t >> 6;
        const int lane = t & 63;
        const int hbase = rg*64 + wid*16;
        const f32x4 aB = *(const f32x4*)(a + lane*4);
        const f32x4 aA = *(const f32x4*)(a + HH + lane*4);
#pragma unroll 4
        for (int rr = 0; rr < 16; ++rr) {
            const int h = hbase + rr;
            const f32x4 w4 = *(const f32x4*)(w + z*HH*HH + h*HH + lane*4);
            float dA = w4.x*aA.x + w4.y*aA.y + w4.z*aA.z + w4.w*aA.w;
            float dB = w4.x*aB.x + w4.y*aB.y + w4.z*aB.z + w4.w*aB.w;
#pragma unroll
            for (int off = 32; off; off >>= 1) {
                dA += __shfl_xor(dA, off);
                dB += __shfl_xor(dB, off);
            }
            if (lane == 0) { WA[z*HH + h] = dA; WB[z*HH + h] = dB; }
        }
    } else if (b < 208) {
        const int d = b - 144;                 // WgT[h][d] = bf16(Wg[d][h])
        WgT[t*64 + d] = f2bf(Wg[d*HH + t]);
    } else {
        const int kb = b - 208;                // 4 k-rows per block
#pragma unroll
        for (int kk = 0; kk < 4; ++kk) {
            const int k = kb*4 + kk;
            float x  = w[k*HH + t];
            ushort hi = f2bf(x);
            __hip_bfloat16 hb = *reinterpret_cast<__hip_bfloat16*>(&hi);
            ushort lo = f2bf(x - __bfloat162float(hb));
            W2hi[t*1024 + k] = hi;
            W2lo[t*1024 + k] = lo;
        }
    }
}

// grid 1024: block = (quarter qq, n); j in [qq*64, qq*64+64), 4 chunks of 16.
// One barrier per chunk: A-frags built in regs from Q (no staging LDS);
// softmax redundant per-wave, lane-parallel (lane = (z,j)); m/l in registers.
__global__ __launch_bounds__(256) void gat_partial_kernel(
    const float* __restrict__ ahs, const float* __restrict__ ghs,
    const float* __restrict__ b_gate, float* __restrict__ ws)
{
    const int n    = blockIdx.x & 255;
    const int qq   = blockIdx.x >> 8;
    const int t    = threadIdx.x;
    const int wid  = t >> 6;
    const int lane = t & 63;
    const int quad = lane >> 4;
    const int l15  = lane & 15;
    const int zg   = quad;              // softmax lane-group z = lane>>4
    const int jj   = l15;               // softmax lane j
    const int n0   = wid * 64;

    const float* P  = ws + WS_P;
    const float* Q  = ws + WS_Q;
    const float* T  = ws + WS_T;
    const float* WA = ws + WS_WA;
    const float* WB = ws + WS_WB;
    const ushort* WgT = (const ushort*)(ws + WS_WGT);
    float* PV = ws + WS_PV;
    float* ML = ws + WS_ML;

    __shared__ __align__(16) float part[2][4][16][4];    // [parity][z][j][wid]
    __shared__ __align__(16) float alpha_w[4][16][4];    // [wid][j][z] per-wave private
    __shared__ float vred[4][4][260];

    int hcol[4];
#pragma unroll
    for (int nt = 0; nt < 4; ++nt) hcol[nt] = n0 + nt*16 + l15;

    short8 bfrag[4][2];
    float  wa_reg[4][4];
    float  bgv[4];
#pragma unroll
    for (int nt = 0; nt < 4; ++nt) {
#pragma unroll
        for (int kh = 0; kh < 2; ++kh)
            bfrag[nt][kh] = *(const short8*)(WgT + hcol[nt]*64 + kh*32 + quad*8);
#pragma unroll
        for (int z = 0; z < 4; ++z) wa_reg[z][nt] = WA[z*HH + hcol[nt]];
        bgv[nt] = b_gate[hcol[nt]];
    }

    // P columns this lane consumes in A-frags: k = kh*32 + quad*8 + i
    float pnA[2][8];
#pragma unroll
    for (int kh = 0; kh < 2; ++kh) {
        *(f32x4*)&pnA[kh][0] = *(const f32x4*)(P + n*64 + kh*32 + quad*8);
        *(f32x4*)&pnA[kh][4] = *(const f32x4*)(P + n*64 + kh*32 + quad*8 + 4);
    }

    // vacc [z][nt]; k=0 self term carried by quarter 0, quad 0
    float vacc[4][4];
    {
        float av[4];
#pragma unroll
        for (int nt = 0; nt < 4; ++nt) av[nt] = ahs[n*HH + hcol[nt]];
#pragma unroll
        for (int z = 0; z < 4; ++z)
#pragma unroll
            for (int nt = 0; nt < 4; ++nt)
                vacc[z][nt] = (qq == 0 && quad == 0) ? av[nt] : 0.f;
    }

    // init softmax state, redundant per wave, lane-group parallel:
    // lane (zg, jj): partial over h = jj*16 .. jj*16+16, then red16.
    float cz_r, m_r, l_r;
    {
        float pc = 0.f, ps = 0.f;
        const int hb = jj*16;
#pragma unroll
        for (int i4 = 0; i4 < 4; ++i4) {
            f32x4 av = *(const f32x4*)(ahs + n*HH + hb + i4*4);
            f32x4 wb = *(const f32x4*)(WB + zg*HH + hb + i4*4);
            f32x4 wa = *(const f32x4*)(WA + zg*HH + hb + i4*4);
            pc = fmaf(av.x, wb.x, pc); pc = fmaf(av.y, wb.y, pc);
            pc = fmaf(av.z, wb.z, pc); pc = fmaf(av.w, wb.w, pc);
            ps = fmaf(av.x, wa.x, ps); ps = fmaf(av.y, wa.y, ps);
            ps = fmaf(av.z, wa.z, ps); ps = fmaf(av.w, wa.w, ps);
        }
        pc = red16(pc); ps = red16(ps);
        cz_r = pc;
        if (qq == 0) {
            float sc = pc + ps;
            m_r = sc > 0.f ? sc : 0.2f * sc;
            l_r = 1.0f;
        } else {
            m_r = -__builtin_inff();
            l_r = 0.0f;
        }
    }

    for (int cc = 0; cc < 4; ++cc) {
        const int j0  = qq*64 + cc*16;
        const int par = cc & 1;

        // T prefetch (independent of MFMA chain)
        float tval[4][4];
#pragma unroll
        for (int r = 0; r < 4; ++r) {
            const int jg = j0 + quad*4 + r;
#pragma unroll
            for (int nt = 0; nt < 4; ++nt)
                tval[nt][r] = T[jg*HH + hcol[nt]];
        }

        // A-frags straight from Q (register build, no LDS)
        short8 afrag[2];
#pragma unroll
        for (int kh = 0; kh < 2; ++kh) {
            const float* qrow = Q + (j0 + l15)*64 + kh*32 + quad*8;
            f32x4 qa = *(const f32x4*)qrow;
            f32x4 qb = *(const f32x4*)(qrow + 4);
            ushort hv[8];
            hv[0] = f2bf(fmaxf(pnA[kh][0] + qa.x, 0.f));
            hv[1] = f2bf(fmaxf(pnA[kh][1] + qa.y, 0.f));
            hv[2] = f2bf(fmaxf(pnA[kh][2] + qa.z, 0.f));
            hv[3] = f2bf(fmaxf(pnA[kh][3] + qa.w, 0.f));
            hv[4] = f2bf(fmaxf(pnA[kh][4] + qb.x, 0.f));
            hv[5] = f2bf(fmaxf(pnA[kh][5] + qb.y, 0.f));
            hv[6] = f2bf(fmaxf(pnA[kh][6] + qb.z, 0.f));
            hv[7] = f2bf(fmaxf(pnA[kh][7] + qb.w, 0.f));
            afrag[kh] = *(short8*)hv;
        }

        f32x4 acc[4];
#pragma unroll
        for (int nt = 0; nt < 4; ++nt) acc[nt] = (f32x4){0.f,0.f,0.f,0.f};
#pragma unroll
        for (int nt = 0; nt < 4; ++nt) {
            acc[nt] = __builtin_amdgcn_mfma_f32_16x16x32_bf16(
                afrag[0], bfrag[nt][0], acc[nt], 0, 0, 0);
            acc[nt] = __builtin_amdgcn_mfma_f32_16x16x32_bf16(
                afrag[1], bfrag[nt][1], acc[nt], 0, 0, 0);
        }

        // gate epilogue in regs (T resident)
        float vals[4][4];   // [nt][r]
#pragma unroll
        for (int r = 0; r < 4; ++r) {
            const int jg = j0 + quad*4 + r;
            const bool diag = (jg == n);
#pragma unroll
            for (int nt = 0; nt < 4; ++nt) {
                float u = acc[nt][r] + bgv[nt];
                float val;
                if (diag) {
                    val = ghs[n*HH + hcol[nt]];
                } else {
                    float g = 1.0f / (1.0f + __expf(-u));
                    val = g * tval[nt][r];
                }
                vals[nt][r] = val;
            }
        }

        // score partials, 16-lane reduce, one LDS write per (z,r)
        float ppv[4][4];
#pragma unroll
        for (int z = 0; z < 4; ++z)
#pragma unroll
            for (int r = 0; r < 4; ++r) {
                float s = 0.f;
#pragma unroll
                for (int nt = 0; nt < 4; ++nt)
                    s = fmaf(vals[nt][r], wa_reg[z][nt], s);
                ppv[z][r] = red16(s);
            }
        if (l15 < 4) {
#pragma unroll
            for (int r = 0; r < 4; ++r) {
                float v = (l15 == 0) ? ppv[0][r] : (l15 == 1) ? ppv[1][r]
                        : (l15 == 2) ? ppv[2][r] : ppv[3][r];
                part[par][l15][quad*4 + r][wid] = v;
            }
        }
        __syncthreads();   // the ONLY barrier per chunk

        // lane-parallel softmax, redundant in every wave (identical results)
        float scl0, scl1, scl2, scl3;
        {
            f32x4 pr = *(const f32x4*)&part[par][zg][jj][0];
            float s = cz_r + ((pr.x + pr.y) + (pr.z + pr.w));
            float e = s > 0.f ? s : 0.2f * s;
            float mx = red16max(e);
            float m_new = fmaxf(m_r, mx);
            float at = __expf(e - m_new);
            float ss = red16(at);
            float scale = __expf(m_r - m_new);
            l_r = l_r * scale + ss;
            m_r = m_new;
            alpha_w[wid][jj][zg] = at;        // within-wave LDS, no barrier needed
            scl0 = __shfl(scale, 0);
            scl1 = __shfl(scale, 16);
            scl2 = __shfl(scale, 32);
            scl3 = __shfl(scale, 48);
        }
#pragma unroll
        for (int nt = 0; nt < 4; ++nt) {
            vacc[0][nt] *= scl0; vacc[1][nt] *= scl1;
            vacc[2][nt] *= scl2; vacc[3][nt] *= scl3;
        }
#pragma unroll
        for (int r = 0; r < 4; ++r) {
            f32x4 al = *(const f32x4*)&alpha_w[wid][quad*4 + r][0];
#pragma unroll
            for (int nt = 0; nt < 4; ++nt) {
                float v = vals[nt][r];
                vacc[0][nt] = fmaf(al.x, v, vacc[0][nt]);
                vacc[1][nt] = fmaf(al.y, v, vacc[1][nt]);
                vacc[2][nt] = fmaf(al.z, v, vacc[2][nt]);
                vacc[3][nt] = fmaf(al.w, v, vacc[3][nt]);
            }
        }
    }

    // cross-quad reduce, write unnormalized PV + (m,l)
#pragma unroll
    for (int z = 0; z < 4; ++z)
#pragma unroll
        for (int nt = 0; nt < 4; ++nt)
            vred[quad][z][hcol[nt]] = vacc[z][nt];
    __syncthreads();
#pragma unroll
    for (int z = 0; z < 4; ++z) {
        float s = (vred[0][z][t] + vred[1][z][t]) + (vred[2][z][t] + vred[3][z][t]);
        PV[((qq*4 + z)*NN + n)*HH + t] = s;
    }
    if (wid == 0 && l15 == 0) {   // lanes 0,16,32,48 -> z = quad
        ML[((qq*4 + quad)*NN + n)*2 + 0] = m_r;
        ML[((qq*4 + quad)*NN + n)*2 + 1] = l_r;
    }
}

// grid 256: merge quarters, normalize, split to bf16 hi/lo VN
__global__ __launch_bounds__(256) void gat_merge_kernel(float* __restrict__ ws)
{
    const int n = blockIdx.x;
    const int t = threadIdx.x;
    const float* PV = ws + WS_PV;
    const float* ML = ws + WS_ML;
    ushort* VNhi = (ushort*)(ws + WS_VNH);
    ushort* VNlo = (ushort*)(ws + WS_VNL);

    __shared__ float sq[4][4];
    if (t < 4) {
        float m[4], l[4];
#pragma unroll
        for (int q = 0; q < 4; ++q) {
            m[q] = ML[((q*4 + t)*NN + n)*2 + 0];
            l[q] = ML[((q*4 + t)*NN + n)*2 + 1];
        }
        float mm = fmaxf(fmaxf(m[0], m[1]), fmaxf(m[2], m[3]));
        float s0 = __expf(m[0]-mm), s1 = __expf(m[1]-mm);
        float s2 = __expf(m[2]-mm), s3 = __expf(m[3]-mm);
        float inv = 1.0f / (l[0]*s0 + l[1]*s1 + l[2]*s2 + l[3]*s3);
        sq[t][0] = s0*inv; sq[t][1] = s1*inv; sq[t][2] = s2*inv; sq[t][3] = s3*inv;
    }
    __syncthreads();
#pragma unroll
    for (int z = 0; z < 4; ++z) {
        float v = 0.f;
#pragma unroll
        for (int q = 0; q < 4; ++q)
            v = fmaf(sq[z][q], PV[((q*4 + z)*NN + n)*HH + t], v);
        ushort hi = f2bf(v);
        __hip_bfloat16 hb = *reinterpret_cast<__hip_bfloat16*>(&hi);
        ushort lo = f2bf(v - __bfloat162float(hb));
        VNhi[n*1024 + z*HH + t] = hi;
        VNlo[n*1024 + z*HH + t] = lo;
    }
}

// grid 16: out = relu(0.25 * VN @ w) + bias via split-bf16 MFMA (3 terms).
// block = 64n x 64f; wave = 16n x 64f; K=1024 in 32 steps, frags from global.
__global__ __launch_bounds__(256) void gat_out_kernel(
    const float* __restrict__ bias, const float* __restrict__ ws,
    float* __restrict__ out)
{
    const int n0b = (blockIdx.x >> 2) * 64;
    const int f0  = (blockIdx.x & 3) * 64;
    const int t    = threadIdx.x;
    const int wid  = t >> 6;
    const int lane = t & 63;
    const int quad = lane >> 4;
    const int l15  = lane & 15;
    const int n0   = n0b + wid*16;

    const ushort* VNhi = (const ushort*)(ws + WS_VNH);
    const ushort* VNlo = (const ushort*)(ws + WS_VNL);
    const ushort* W2hi = (const ushort*)(ws + WS_W2H);
    const ushort* W2lo = (const ushort*)(ws + WS_W2L);

    f32x4 acc[4];
#pragma unroll
    for (int nt = 0; nt < 4; ++nt) acc[nt] = (f32x4){0.f,0.f,0.f,0.f};

    const ushort* arow_h = VNhi + (n0 + l15)*1024 + quad*8;
    const ushort* arow_l = VNlo + (n0 + l15)*1024 + quad*8;

    for (int ks = 0; ks < 32; ++ks) {
        const int k0 = ks * 32;
        short8 ah = *(const short8*)(arow_h + k0);
        short8 al = *(const short8*)(arow_l + k0);
#pragma unroll
        for (int nt = 0; nt < 4; ++nt) {
            const ushort* bbase = W2hi + (f0 + nt*16 + l15)*1024 + k0 + quad*8;
            short8 bh = *(const short8*)bbase;
            short8 bl = *(const short8*)(bbase + (WS_W2L - WS_W2H)*2);
            acc[nt] = __builtin_amdgcn_mfma_f32_16x16x32_bf16(ah, bh, acc[nt], 0, 0, 0);
            acc[nt] = __builtin_amdgcn_mfma_f32_16x16x32_bf16(ah, bl, acc[nt], 0, 0, 0);
            acc[nt] = __builtin_amdgcn_mfma_f32_16x16x32_bf16(al, bh, acc[nt], 0, 0, 0);
        }
    }

#pragma unroll
    for (int nt = 0; nt < 4; ++nt) {
        const int f = f0 + nt*16 + l15;
        float bv = bias[f];
#pragma unroll
        for (int r = 0; r < 4; ++r) {
            const int nrow = n0 + quad*4 + r;
            out[nrow*HH + f] = fmaxf(0.25f * acc[nt][r], 0.f) + bv;
        }
    }
}

extern "C" void kernel_launch(void* const* d_in, const int* in_sizes, int n_in,
                              void* d_out, int out_size, void* d_ws, size_t ws_size,
                              hipStream_t stream)
{
    const float* ahs    = (const float*)d_in[0];
    const float* ghs    = (const float*)d_in[1];
    const float* goal   = (const float*)d_in[2];
    const float* action = (const float*)d_in[3];
    const float* Wd     = (const float*)d_in[4];
    const float* b_dist = (const float*)d_in[5];
    const float* Wg     = (const float*)d_in[6];
    const float* b_gate = (const float*)d_in[7];
    const float* w      = (const float*)d_in[8];
    const float* a      = (const float*)d_in[9];
    const float* bias   = (const float*)d_in[10];
    float* ws   = (float*)d_ws;     // needs 6,758,400 bytes
    float* outp = (float*)d_out;

    precompute_kernel<<<464, 256, 0, stream>>>(ahs, goal, action, Wd, b_dist, Wg, w, a, ws);
    gat_partial_kernel<<<1024, 256, 0, stream>>>(ahs, ghs, b_gate, ws);
    gat_merge_kernel<<<256, 256, 0, stream>>>(ws);
    gat_out_kernel<<<16, 256, 0, stream>>>(bias, ws, outp);
}

// Round 8
// 128.188 us; speedup vs baseline: 1.2649x; 1.2649x over previous
//
#include <hip/hip_runtime.h>
#include <hip/hip_bf16.h>

#define NN 256
#define HH 256

typedef __attribute__((ext_vector_type(8))) short short8;
typedef __attribute__((ext_vector_type(4))) float f32x4;
typedef __attribute__((ext_vector_type(4))) unsigned short su4;

__device__ __forceinline__ ushort f2bf(float x) {
    __hip_bfloat16 h = __float2bfloat16(x);
    return *reinterpret_cast<ushort*>(&h);
}
__device__ __forceinline__ float bf2f(ushort u) {
    __hip_bfloat16 h = *reinterpret_cast<__hip_bfloat16*>(&u);
    return __bfloat162float(h);
}
template <int CTRL>
__device__ __forceinline__ float dpp_add(float x) {
    int y = __builtin_amdgcn_update_dpp(0, __float_as_int(x), CTRL, 0xF, 0xF, true);
    return x + __int_as_float(y);
}
template <int CTRL>
__device__ __forceinline__ float dpp_max(float x) {
    int y = __builtin_amdgcn_update_dpp(0, __float_as_int(x), CTRL, 0xF, 0xF, true);
    return fmaxf(x, __int_as_float(y));
}
__device__ __forceinline__ float red16(float v) {      // sum within 16-lane group
    v = dpp_add<0xB1>(v); v = dpp_add<0x4E>(v);
    v = dpp_add<0x141>(v); v = dpp_add<0x140>(v);
    return v;
}
__device__ __forceinline__ float red16max(float v) {   // max within 16-lane group
    v = dpp_max<0xB1>(v); v = dpp_max<0x4E>(v);
    v = dpp_max<0x141>(v); v = dpp_max<0x140>(v);
    return v;
}

// Workspace (float offsets), total 1,428,480 floats = 5,713,920 B
#define WS_P   0         // P[256][64]
#define WS_Q   16384     // Q[256][64]
#define WS_T   32768     // T[256][256]
#define WS_WA  98304     // WA[4][256]
#define WS_WB  99328     // WB[4][256]
#define WS_WGT 100352    // WgT ushort[256][72]  (padded rows, 9216 floats)
#define WS_PV  109568    // PV[4][4][256][256]
#define WS_ML  1158144   // ML[4][4][256][2]
#define WS_W2H 1166336   // W2hi ushort[256f][1024k]
#define WS_W2L 1297408   // W2lo ushort[256f][1024k]

// grid 272: [0,64) tanh T | [64,128) P/Q | [128,144) WA/WB | [144,208) WgT | [208,272) W2 transpose
__global__ __launch_bounds__(256) void precompute_kernel(
    const float* __restrict__ ahs, const float* __restrict__ goal,
    const float* __restrict__ action, const float* __restrict__ Wd,
    const float* __restrict__ b_dist, const float* __restrict__ Wg,
    const float* __restrict__ w, const float* __restrict__ a,
    float* __restrict__ ws)
{
    const int b = blockIdx.x;
    const int t = threadIdx.x;
    float* P  = ws + WS_P;
    float* Q  = ws + WS_Q;
    float* T  = ws + WS_T;
    float* WA = ws + WS_WA;
    float* WB = ws + WS_WB;
    ushort* WgT  = (ushort*)(ws + WS_WGT);
    ushort* W2hi = (ushort*)(ws + WS_W2H);
    ushort* W2lo = (ushort*)(ws + WS_W2L);

    __shared__ __align__(16) float tile[64][65];

    if (b < 64) {
        const int idx = (b*256 + t)*4;
        float4 v = *(const float4*)(ahs + idx);
        float4 o;
        o.x = tanhf(v.x); o.y = tanhf(v.y); o.z = tanhf(v.z); o.w = tanhf(v.w);
        *(float4*)(T + idx) = o;
    } else if (b < 128) {
        const int i = (b - 64)*4 + (t >> 6);
        const int d = t & 63;
        float a0 = action[2*i], a1 = action[2*i+1];
        float g0 = goal[2*i],   g1 = goal[2*i+1];
        P[i*64 + d] = a0*Wd[0*64+d] + a1*Wd[1*64+d]
                    + g0*Wd[2*64+d] + g1*Wd[3*64+d] + b_dist[d];
        Q[i*64 + d] = a0*Wd[4*64+d] + a1*Wd[5*64+d]
                    + g0*Wd[6*64+d] + g1*Wd[7*64+d];
    } else if (b < 144) {
        const int r    = b - 128;
        const int z    = r >> 2;
        const int rg   = r & 3;
        const int wid  = t >> 6;
        const int lane = t & 63;
        const int hbase = rg*64 + wid*16;
        const f32x4 aB = *(const f32x4*)(a + lane*4);
        const f32x4 aA = *(const f32x4*)(a + HH + lane*4);
#pragma unroll 4
        for (int rr = 0; rr < 16; ++rr) {
            const int h = hbase + rr;
            const f32x4 w4 = *(const f32x4*)(w + z*HH*HH + h*HH + lane*4);
            float dA = w4.x*aA.x + w4.y*aA.y + w4.z*aA.z + w4.w*aA.w;
            float dB = w4.x*aB.x + w4.y*aB.y + w4.z*aB.z + w4.w*aB.w;
#pragma unroll
            for (int off = 32; off; off >>= 1) {
                dA += __shfl_xor(dA, off);
                dB += __shfl_xor(dB, off);
            }
            if (lane == 0) { WA[z*HH + h] = dA; WB[z*HH + h] = dB; }
        }
    } else if (b < 208) {
        const int d = b - 144;                 // WgT[h][d] = bf16(Wg[d][h]), padded row 72
        WgT[t*72 + d] = f2bf(Wg[d*HH + t]);
    } else {
        // W2 transpose: tile (64k x 64f), coalesced read + coalesced write
        const int idx = b - 208;               // 0..63
        const int k0  = (idx >> 2) * 64;
        const int f0  = (idx & 3) * 64;
        const int r   = t >> 6;                // wave id 0..3
        const int ff  = t & 63;
#pragma unroll 4
        for (int i = 0; i < 16; ++i) {
            const int kk = i*4 + r;
            tile[kk][ff] = w[(k0 + kk)*HH + f0 + ff];
        }
        __syncthreads();
#pragma unroll 4
        for (int i = 0; i < 16; ++i) {
            const int fl = i*4 + r;            // local f
            float x = tile[ff][fl];            // = w[k0+ff][f0+fl]
            ushort hi = f2bf(x);
            ushort lo = f2bf(x - bf2f(hi));
            W2hi[(size_t)(f0 + fl)*1024 + k0 + ff] = hi;
            W2lo[(size_t)(f0 + fl)*1024 + k0 + ff] = lo;
        }
    }
}

// grid 1024: block = (quarter qq, n); j in [qq*64, qq*64+64), 4 chunks of 16.
// Wg streamed from a block-local LDS copy (frees 32 persistent VGPRs -> no spills
// at (256,4)); one barrier per chunk; softmax redundant per-wave in registers.
__global__ __launch_bounds__(256, 4) void gat_partial_kernel(
    const float* __restrict__ ahs, const float* __restrict__ ghs,
    const float* __restrict__ b_gate, float* __restrict__ ws)
{
    const int n    = blockIdx.x & 255;
    const int qq   = blockIdx.x >> 8;
    const int t    = threadIdx.x;
    const int wid  = t >> 6;
    const int lane = t & 63;
    const int quad = lane >> 4;
    const int l15  = lane & 15;
    const int zg   = quad;              // softmax lane-group z
    const int jj   = l15;               // softmax lane j
    const int n0   = wid * 64;

    const float* P  = ws + WS_P;
    const float* Q  = ws + WS_Q;
    const float* T  = ws + WS_T;
    const float* WA = ws + WS_WA;
    const float* WB = ws + WS_WB;
    const ushort* WgTg = (const ushort*)(ws + WS_WGT);
    float* PV = ws + WS_PV;
    float* ML = ws + WS_ML;

    __shared__ __align__(16) ushort wg_lds[256][72];      // 36,864 B; aliased by vred after loop
    __shared__ __align__(16) float part[2][4][16][4];
    __shared__ __align__(16) float alpha_w[4][16][4];
    float* vred = (float*)&wg_lds[0][0];                  // [quad*4+z][260] after K-loop

    // stage Wg (padded) into LDS: 2304 x 16B, 9 per thread
    {
        const short8* src = (const short8*)WgTg;
        short8* dst = (short8*)&wg_lds[0][0];
#pragma unroll
        for (int i = 0; i < 9; ++i) dst[i*256 + t] = src[i*256 + t];
    }

    int hcol[4];
#pragma unroll
    for (int nt = 0; nt < 4; ++nt) hcol[nt] = n0 + nt*16 + l15;

    float wa_reg[4][4];
    float bgv[4], gval[4];
#pragma unroll
    for (int nt = 0; nt < 4; ++nt) {
#pragma unroll
        for (int z = 0; z < 4; ++z) wa_reg[z][nt] = WA[z*HH + hcol[nt]];
        bgv[nt]  = b_gate[hcol[nt]];
        gval[nt] = ghs[n*HH + hcol[nt]];
    }

    float pnA[2][8];
#pragma unroll
    for (int kh = 0; kh < 2; ++kh) {
        *(f32x4*)&pnA[kh][0] = *(const f32x4*)(P + n*64 + kh*32 + quad*8);
        *(f32x4*)&pnA[kh][4] = *(const f32x4*)(P + n*64 + kh*32 + quad*8 + 4);
    }

    float vacc[4][4];
    {
        float av[4];
#pragma unroll
        for (int nt = 0; nt < 4; ++nt) av[nt] = ahs[n*HH + hcol[nt]];
#pragma unroll
        for (int z = 0; z < 4; ++z)
#pragma unroll
            for (int nt = 0; nt < 4; ++nt)
                vacc[z][nt] = (qq == 0 && quad == 0) ? av[nt] : 0.f;
    }

    // softmax init (redundant per wave): lane (zg,jj) sums h = jj*16..jj*16+16
    float cz_r, m_r, l_r;
    {
        float pc = 0.f, ps = 0.f;
        const int hb = jj*16;
#pragma unroll
        for (int i4 = 0; i4 < 4; ++i4) {
            f32x4 av = *(const f32x4*)(ahs + n*HH + hb + i4*4);
            f32x4 wb = *(const f32x4*)(WB + zg*HH + hb + i4*4);
            f32x4 wa = *(const f32x4*)(WA + zg*HH + hb + i4*4);
            pc = fmaf(av.x, wb.x, pc); pc = fmaf(av.y, wb.y, pc);
            pc = fmaf(av.z, wb.z, pc); pc = fmaf(av.w, wb.w, pc);
            ps = fmaf(av.x, wa.x, ps); ps = fmaf(av.y, wa.y, ps);
            ps = fmaf(av.z, wa.z, ps); ps = fmaf(av.w, wa.w, ps);
        }
        pc = red16(pc); ps = red16(ps);
        cz_r = pc;
        if (qq == 0) {
            float sc = pc + ps;
            m_r = sc > 0.f ? sc : 0.2f * sc;
            l_r = 1.0f;
        } else {
            m_r = -__builtin_inff();
            l_r = 0.0f;
        }
    }
    __syncthreads();   // wg_lds staged

    for (int cc = 0; cc < 4; ++cc) {
        const int j0  = qq*64 + cc*16;
        const int par = cc & 1;

        // T prefetch (independent loads)
        float tval[4][4];
#pragma unroll
        for (int r = 0; r < 4; ++r) {
            const int jg = j0 + quad*4 + r;
#pragma unroll
            for (int nt = 0; nt < 4; ++nt)
                tval[nt][r] = T[jg*HH + hcol[nt]];
        }

        // A-frags from Q + P (registers)
        short8 afrag[2];
#pragma unroll
        for (int kh = 0; kh < 2; ++kh) {
            const float* qrow = Q + (j0 + l15)*64 + kh*32 + quad*8;
            f32x4 qa = *(const f32x4*)qrow;
            f32x4 qb = *(const f32x4*)(qrow + 4);
            ushort hv[8];
            hv[0] = f2bf(fmaxf(pnA[kh][0] + qa.x, 0.f));
            hv[1] = f2bf(fmaxf(pnA[kh][1] + qa.y, 0.f));
            hv[2] = f2bf(fmaxf(pnA[kh][2] + qa.z, 0.f));
            hv[3] = f2bf(fmaxf(pnA[kh][3] + qa.w, 0.f));
            hv[4] = f2bf(fmaxf(pnA[kh][4] + qb.x, 0.f));
            hv[5] = f2bf(fmaxf(pnA[kh][5] + qb.y, 0.f));
            hv[6] = f2bf(fmaxf(pnA[kh][6] + qb.z, 0.f));
            hv[7] = f2bf(fmaxf(pnA[kh][7] + qb.w, 0.f));
            afrag[kh] = *(short8*)hv;
        }

        // MFMA, B streamed from LDS (2-way bank-free: row stride 144B)
        f32x4 acc[4];
#pragma unroll
        for (int nt = 0; nt < 4; ++nt) {
            short8 b0 = *(const short8*)&wg_lds[hcol[nt]][quad*8];
            short8 b1 = *(const short8*)&wg_lds[hcol[nt]][32 + quad*8];
            f32x4 a4 = (f32x4){0.f,0.f,0.f,0.f};
            a4 = __builtin_amdgcn_mfma_f32_16x16x32_bf16(afrag[0], b0, a4, 0, 0, 0);
            a4 = __builtin_amdgcn_mfma_f32_16x16x32_bf16(afrag[1], b1, a4, 0, 0, 0);
            acc[nt] = a4;
        }

        // gate epilogue (T resident, diag from gval regs)
        float vals[4][4];
#pragma unroll
        for (int r = 0; r < 4; ++r) {
            const int jg = j0 + quad*4 + r;
            const bool diag = (jg == n);
#pragma unroll
            for (int nt = 0; nt < 4; ++nt) {
                float u = acc[nt][r] + bgv[nt];
                float g = 1.0f / (1.0f + __expf(-u));
                vals[nt][r] = diag ? gval[nt] : g * tval[nt][r];
            }
        }

        // score partials: per z reduce + LDS write (lane l15==z)
#pragma unroll
        for (int z = 0; z < 4; ++z) {
            float pp[4];
#pragma unroll
            for (int r = 0; r < 4; ++r) {
                float s = 0.f;
#pragma unroll
                for (int nt = 0; nt < 4; ++nt)
                    s = fmaf(vals[nt][r], wa_reg[z][nt], s);
                pp[r] = red16(s);
            }
            if (l15 == z) {
#pragma unroll
                for (int r = 0; r < 4; ++r)
                    part[par][z][quad*4 + r][wid] = pp[r];
            }
        }
        __syncthreads();   // the only barrier per chunk

        // redundant lane-parallel softmax
        float scl0, scl1, scl2, scl3;
        {
            f32x4 pr = *(const f32x4*)&part[par][zg][jj][0];
            float s = cz_r + ((pr.x + pr.y) + (pr.z + pr.w));
            float e = s > 0.f ? s : 0.2f * s;
            float mx = red16max(e);
            float m_new = fmaxf(m_r, mx);
            float at = __expf(e - m_new);
            float ss = red16(at);
            float scale = __expf(m_r - m_new);
            l_r = l_r * scale + ss;
            m_r = m_new;
            alpha_w[wid][jj][zg] = at;      // per-wave private
            scl0 = __shfl(scale, 0);
            scl1 = __shfl(scale, 16);
            scl2 = __shfl(scale, 32);
            scl3 = __shfl(scale, 48);
        }
#pragma unroll
        for (int nt = 0; nt < 4; ++nt) {
            vacc[0][nt] *= scl0; vacc[1][nt] *= scl1;
            vacc[2][nt] *= scl2; vacc[3][nt] *= scl3;
        }
#pragma unroll
        for (int r = 0; r < 4; ++r) {
            f32x4 al = *(const f32x4*)&alpha_w[wid][quad*4 + r][0];
#pragma unroll
            for (int nt = 0; nt < 4; ++nt) {
                float v = vals[nt][r];
                vacc[0][nt] = fmaf(al.x, v, vacc[0][nt]);
                vacc[1][nt] = fmaf(al.y, v, vacc[1][nt]);
                vacc[2][nt] = fmaf(al.z, v, vacc[2][nt]);
                vacc[3][nt] = fmaf(al.w, v, vacc[3][nt]);
            }
        }
    }
    // wg_lds reads all drained at the last in-loop barrier; safe to alias as vred

#pragma unroll
    for (int z = 0; z < 4; ++z)
#pragma unroll
        for (int nt = 0; nt < 4; ++nt)
            vred[(quad*4 + z)*260 + hcol[nt]] = vacc[z][nt];
    __syncthreads();
#pragma unroll
    for (int z = 0; z < 4; ++z) {
        float s = (vred[(0*4+z)*260 + t] + vred[(1*4+z)*260 + t])
                + (vred[(2*4+z)*260 + t] + vred[(3*4+z)*260 + t]);
        PV[((qq*4 + z)*NN + n)*HH + t] = s;
    }
    if (wid == 0 && l15 == 0) {
        ML[((qq*4 + zg)*NN + n)*2 + 0] = m_r;
        ML[((qq*4 + zg)*NN + n)*2 + 1] = l_r;
    }
}

// grid 64: (16 n-tiles) x (4 f-tiles). Fused merge + split-bf16 MFMA projection.
__global__ __launch_bounds__(256) void gat_out_kernel(
    const float* __restrict__ bias, const float* __restrict__ ws,
    float* __restrict__ out)
{
    const int n0 = (blockIdx.x >> 2) * 16;
    const int f0 = (blockIdx.x & 3) * 64;
    const int t    = threadIdx.x;
    const int wid  = t >> 6;
    const int lane = t & 63;
    const int quad = lane >> 4;
    const int l15  = lane & 15;

    const float* PV = ws + WS_PV;
    const float* ML = ws + WS_ML;
    const ushort* W2hi = (const ushort*)(ws + WS_W2H);
    const ushort* W2lo = (const ushort*)(ws + WS_W2L);

    __shared__ __align__(16) char smx[67072];
    ushort (*VNh)[1032] = (ushort(*)[1032])smx;                 // 33,024 B
    ushort (*VNl)[1032] = (ushort(*)[1032])(smx + 33024);       // 33,024 B
    float  (*sq)[4][4]  = (float(*)[4][4])(smx + 66048);        // 1,024 B
    float* red = (float*)smx;                                   // [3][4][16][16] aliases VN after MFMA

    // Phase A: per (n_i,z,q) softmax-merge scales; t = n_i*16 + z*4 + q
    {
        const int n_i = t >> 4, z = (t >> 2) & 3, q = t & 3;
        float m = ML[((q*4 + z)*NN + n0 + n_i)*2 + 0];
        float l = ML[((q*4 + z)*NN + n0 + n_i)*2 + 1];
        float mm = fmaxf(m, __shfl_xor(m, 1));
        mm = fmaxf(mm, __shfl_xor(mm, 2));
        float s  = __expf(m - mm);
        float ls = l * s;
        ls += __shfl_xor(ls, 1);
        ls += __shfl_xor(ls, 2);
        sq[n_i][z][q] = s / ls;
    }
    __syncthreads();

    // Phase B: merged normalized V -> bf16 hi/lo in LDS. thread t covers k = t*4..t*4+4
    {
        const int z  = t >> 6;
        const int kk = (t & 63) * 4;
#pragma unroll 4
        for (int n_i = 0; n_i < 16; ++n_i) {
            const int n = n0 + n_i;
            f32x4 v = (f32x4){0.f,0.f,0.f,0.f};
#pragma unroll
            for (int q = 0; q < 4; ++q) {
                float sc = sq[n_i][z][q];
                f32x4 pv = *(const f32x4*)(PV + ((size_t)(q*4 + z)*NN + n)*HH + kk);
                v.x = fmaf(sc, pv.x, v.x); v.y = fmaf(sc, pv.y, v.y);
                v.z = fmaf(sc, pv.z, v.z); v.w = fmaf(sc, pv.w, v.w);
            }
            ushort hi[4], lo[4];
#pragma unroll
            for (int c = 0; c < 4; ++c) {
                float x = ((float*)&v)[c];
                hi[c] = f2bf(x);
                lo[c] = f2bf(x - bf2f(hi[c]));
            }
            *(su4*)&VNh[n_i][z*256 + kk] = *(su4*)hi;
            *(su4*)&VNl[n_i][z*256 + kk] = *(su4*)lo;
        }
    }
    __syncthreads();

    // Phase C: MFMA, K split across 4 waves (wave wid: k in [wid*256, wid*256+256))
    f32x4 acc[4];
#pragma unroll
    for (int nt = 0; nt < 4; ++nt) acc[nt] = (f32x4){0.f,0.f,0.f,0.f};
    {
        const int wk0 = wid * 256;
        for (int ks = 0; ks < 8; ++ks) {
            const int k0 = wk0 + ks*32;
            short8 ah = *(const short8*)&VNh[l15][k0 + quad*8];
            short8 al = *(const short8*)&VNl[l15][k0 + quad*8];
#pragma unroll
            for (int nt = 0; nt < 4; ++nt) {
                const size_t boff = (size_t)(f0 + nt*16 + l15)*1024 + k0 + quad*8;
                short8 bh = *(const short8*)(W2hi + boff);
                short8 bl = *(const short8*)(W2lo + boff);
                acc[nt] = __builtin_amdgcn_mfma_f32_16x16x32_bf16(ah, bh, acc[nt], 0, 0, 0);
                acc[nt] = __builtin_amdgcn_mfma_f32_16x16x32_bf16(ah, bl, acc[nt], 0, 0, 0);
                acc[nt] = __builtin_amdgcn_mfma_f32_16x16x32_bf16(al, bh, acc[nt], 0, 0, 0);
            }
        }
    }
    __syncthreads();   // VN dead; red aliases it

    // Phase D: cross-wave K reduce + epilogue
    if (wid > 0) {
#pragma unroll
        for (int nt = 0; nt < 4; ++nt)
#pragma unroll
            for (int r = 0; r < 4; ++r)
                red[(((wid-1)*4 + nt)*16 + quad*4 + r)*16 + l15] = acc[nt][r];
    }
    __syncthreads();
    if (wid == 0) {
#pragma unroll
        for (int nt = 0; nt < 4; ++nt) {
            const int f = f0 + nt*16 + l15;
            float bv = bias[f];
#pragma unroll
            for (int r = 0; r < 4; ++r) {
                const int row = quad*4 + r;
                float s = acc[nt][r]
                        + red[((0*4 + nt)*16 + row)*16 + l15]
                        + red[((1*4 + nt)*16 + row)*16 + l15]
                        + red[((2*4 + nt)*16 + row)*16 + l15];
                out[(size_t)(n0 + row)*HH + f] = fmaxf(0.25f * s, 0.f) + bv;
            }
        }
    }
}

extern "C" void kernel_launch(void* const* d_in, const int* in_sizes, int n_in,
                              void* d_out, int out_size, void* d_ws, size_t ws_size,
                              hipStream_t stream)
{
    const float* ahs    = (const float*)d_in[0];
    const float* ghs    = (const float*)d_in[1];
    const float* goal   = (const float*)d_in[2];
    const float* action = (const float*)d_in[3];
    const float* Wd     = (const float*)d_in[4];
    const float* b_dist = (const float*)d_in[5];
    const float* Wg     = (const float*)d_in[6];
    const float* b_gate = (const float*)d_in[7];
    const float* w      = (const float*)d_in[8];
    const float* a      = (const float*)d_in[9];
    const float* bias   = (const float*)d_in[10];
    float* ws   = (float*)d_ws;     // needs 5,713,920 bytes
    float* outp = (float*)d_out;

    precompute_kernel<<<272, 256, 0, stream>>>(ahs, goal, action, Wd, b_dist, Wg, w, a, ws);
    gat_partial_kernel<<<1024, 256, 0, stream>>>(ahs, ghs, b_gate, ws);
    gat_out_kernel<<<64, 256, 0, stream>>>(bias, ws, outp);
}

// Round 10
// 125.489 us; speedup vs baseline: 1.2921x; 1.0215x over previous
//
#include <hip/hip_runtime.h>
#include <hip/hip_bf16.h>

#define NN 256
#define HH 256

typedef __attribute__((ext_vector_type(8))) short short8;
typedef __attribute__((ext_vector_type(4))) float f32x4;

__device__ __forceinline__ ushort f2bf(float x) {
    __hip_bfloat16 h = __float2bfloat16(x);
    return *reinterpret_cast<ushort*>(&h);
}
__device__ __forceinline__ float bf2f(ushort u) {
    __hip_bfloat16 h = *reinterpret_cast<__hip_bfloat16*>(&u);
    return __bfloat162float(h);
}
template <int CTRL>
__device__ __forceinline__ float dpp_add(float x) {
    int y = __builtin_amdgcn_update_dpp(0, __float_as_int(x), CTRL, 0xF, 0xF, true);
    return x + __int_as_float(y);
}
template <int CTRL>
__device__ __forceinline__ float dpp_max(float x) {
    int y = __builtin_amdgcn_update_dpp(0, __float_as_int(x), CTRL, 0xF, 0xF, true);
    return fmaxf(x, __int_as_float(y));
}
__device__ __forceinline__ float red16(float v) {
    v = dpp_add<0xB1>(v); v = dpp_add<0x4E>(v);
    v = dpp_add<0x141>(v); v = dpp_add<0x140>(v);
    return v;
}
__device__ __forceinline__ float red16max(float v) {
    v = dpp_max<0xB1>(v); v = dpp_max<0x4E>(v);
    v = dpp_max<0x141>(v); v = dpp_max<0x140>(v);
    return v;
}

// ws (float offsets), total 899,072 floats = 3,596,288 B
#define WS_P   0        // P[256][64]
#define WS_Q   16384    // Q[256][64]
#define WS_T   32768    // T[256][256]
#define WS_WA  98304    // WA[4][256]
#define WS_WB  99328    // WB[4][256]
#define WS_WGT 100352   // WgT ushort[256][64]
#define WS_PV  108544   // PV[2][4][256][256]
#define WS_ML  632832   // ML[2][4][256][2]
#define WS_W2H 636928   // W2hi ushort[256f][1024k]
#define WS_W2L 768000   // W2lo ushort[256f][1024k]

// grid 272: [0,16) WA/WB | [16,80) W2 transpose | [80,144) P/Q | [144,208) WgT | [208,272) T
__global__ __launch_bounds__(256) void precompute_kernel(
    const float* __restrict__ ahs, const float* __restrict__ goal,
    const float* __restrict__ action, const float* __restrict__ Wd,
    const float* __restrict__ b_dist, const float* __restrict__ Wg,
    const float* __restrict__ w, const float* __restrict__ a,
    float* __restrict__ ws)
{
    const int b = blockIdx.x;
    const int t = threadIdx.x;
    const int wid  = t >> 6;
    const int lane = t & 63;
    float* P  = ws + WS_P;
    float* Q  = ws + WS_Q;
    float* T  = ws + WS_T;
    float* WA = ws + WS_WA;
    float* WB = ws + WS_WB;
    ushort* WgT  = (ushort*)(ws + WS_WGT);
    ushort* W2hi = (ushort*)(ws + WS_W2H);
    ushort* W2lo = (ushort*)(ws + WS_W2L);

    __shared__ __align__(16) float tile[64][65];

    if (b < 16) {
        const int z  = b >> 2;
        const int rg = b & 3;
        const int hbase = rg*64 + wid*16;
        const f32x4 aB = *(const f32x4*)(a + lane*4);
        const f32x4 aA = *(const f32x4*)(a + HH + lane*4);
#pragma unroll 4
        for (int rr = 0; rr < 16; ++rr) {
            const int h = hbase + rr;
            const f32x4 w4 = *(const f32x4*)(w + z*HH*HH + h*HH + lane*4);
            float dA = w4.x*aA.x + w4.y*aA.y + w4.z*aA.z + w4.w*aA.w;
            float dB = w4.x*aB.x + w4.y*aB.y + w4.z*aB.z + w4.w*aB.w;
#pragma unroll
            for (int off = 32; off; off >>= 1) {
                dA += __shfl_xor(dA, off);
                dB += __shfl_xor(dB, off);
            }
            if (lane == 0) { WA[z*HH + h] = dA; WB[z*HH + h] = dB; }
        }
    } else if (b < 80) {
        const int idx = b - 16;
        const int k0  = (idx >> 2) * 64;
        const int f0  = (idx & 3) * 64;
        const int ff  = t & 63;
#pragma unroll 4
        for (int i = 0; i < 16; ++i) {
            const int kk = i*4 + wid;
            tile[kk][ff] = w[(k0 + kk)*HH + f0 + ff];
        }
        __syncthreads();
#pragma unroll 4
        for (int i = 0; i < 16; ++i) {
            const int fl = i*4 + wid;
            float x = tile[ff][fl];
            ushort hi = f2bf(x);
            ushort lo = f2bf(x - bf2f(hi));
            W2hi[(size_t)(f0 + fl)*1024 + k0 + ff] = hi;
            W2lo[(size_t)(f0 + fl)*1024 + k0 + ff] = lo;
        }
    } else if (b < 144) {
        const int i = (b - 80)*4 + wid;
        const int d = lane;
        float a0 = action[2*i], a1 = action[2*i+1];
        float g0 = goal[2*i],   g1 = goal[2*i+1];
        P[i*64 + d] = a0*Wd[0*64+d] + a1*Wd[1*64+d]
                    + g0*Wd[2*64+d] + g1*Wd[3*64+d] + b_dist[d];
        Q[i*64 + d] = a0*Wd[4*64+d] + a1*Wd[5*64+d]
                    + g0*Wd[6*64+d] + g1*Wd[7*64+d];
    } else if (b < 208) {
        const int d = b - 144;
        WgT[t*64 + d] = f2bf(Wg[d*HH + t]);
    } else {
        const int idx = ((b - 208)*256 + t)*4;
        float4 v = *(const float4*)(ahs + idx);
        float4 o;
        o.x = tanhf(v.x); o.y = tanhf(v.y); o.z = tanhf(v.z); o.w = tanhf(v.w);
        *(float4*)(T + idx) = o;
    }
}

// grid 512: block = (n, half hh); j in [hh*128, +128), 8 one-barrier chunks of 16.
// B-fragments persistent in registers; (256,2) -> 256-VGPR budget, no spills.
__global__ __launch_bounds__(256, 2) void gat_partial_kernel(
    const float* __restrict__ ahs, const float* __restrict__ ghs,
    const float* __restrict__ b_gate, float* __restrict__ ws)
{
    const int n    = blockIdx.x >> 1;
    const int hh   = blockIdx.x & 1;
    const int t    = threadIdx.x;
    const int wid  = t >> 6;
    const int lane = t & 63;
    const int quad = lane >> 4;
    const int l15  = lane & 15;
    const int zg   = quad;
    const int jj   = l15;
    const int n0   = wid * 64;

    const float* P  = ws + WS_P;
    const float* Q  = ws + WS_Q;
    const float* T  = ws + WS_T;
    const float* WA = ws + WS_WA;
    const float* WB = ws + WS_WB;
    const ushort* WgT = (const ushort*)(ws + WS_WGT);
    float* PV = ws + WS_PV;
    float* ML = ws + WS_ML;

    __shared__ __align__(16) float part[2][4][16][4];
    __shared__ __align__(16) float alpha_w[4][16][4];
    __shared__ __align__(16) float vred[16][260];

    int hcol[4];
#pragma unroll
    for (int nt = 0; nt < 4; ++nt) hcol[nt] = n0 + nt*16 + l15;

    short8 bfrag[4][2];
    float  wa_reg[4][4];
    float  bgv[4], gval[4];
#pragma unroll
    for (int nt = 0; nt < 4; ++nt) {
#pragma unroll
        for (int kh = 0; kh < 2; ++kh)
            bfrag[nt][kh] = *(const short8*)(WgT + hcol[nt]*64 + kh*32 + quad*8);
#pragma unroll
        for (int z = 0; z < 4; ++z) wa_reg[z][nt] = WA[z*HH + hcol[nt]];
        bgv[nt]  = b_gate[hcol[nt]];
        gval[nt] = ghs[n*HH + hcol[nt]];
    }

    float pnA[2][8];
#pragma unroll
    for (int kh = 0; kh < 2; ++kh) {
        *(f32x4*)&pnA[kh][0] = *(const f32x4*)(P + n*64 + kh*32 + quad*8);
        *(f32x4*)&pnA[kh][4] = *(const f32x4*)(P + n*64 + kh*32 + quad*8 + 4);
    }

    float vacc[4][4];
    {
        float av[4];
#pragma unroll
        for (int nt = 0; nt < 4; ++nt) av[nt] = ahs[n*HH + hcol[nt]];
#pragma unroll
        for (int z = 0; z < 4; ++z)
#pragma unroll
            for (int nt = 0; nt < 4; ++nt)
                vacc[z][nt] = (hh == 0 && quad == 0) ? av[nt] : 0.f;
    }

    // redundant per-wave softmax init: lane (zg,jj) sums h=jj*16..+16
    float cz_r, m_r, l_r;
    {
        float pc = 0.f, ps = 0.f;
        const int hb = jj*16;
#pragma unroll
        for (int i4 = 0; i4 < 4; ++i4) {
            f32x4 av = *(const f32x4*)(ahs + n*HH + hb + i4*4);
            f32x4 wb = *(const f32x4*)(WB + zg*HH + hb + i4*4);
            f32x4 wa = *(const f32x4*)(WA + zg*HH + hb + i4*4);
            pc = fmaf(av.x, wb.x, pc); pc = fmaf(av.y, wb.y, pc);
            pc = fmaf(av.z, wb.z, pc); pc = fmaf(av.w, wb.w, pc);
            ps = fmaf(av.x, wa.x, ps); ps = fmaf(av.y, wa.y, ps);
            ps = fmaf(av.z, wa.z, ps); ps = fmaf(av.w, wa.w, ps);
        }
        pc = red16(pc); ps = red16(ps);
        cz_r = pc;
        if (hh == 0) {
            float sc = pc + ps;
            m_r = sc > 0.f ? sc : 0.2f * sc;
            l_r = 1.0f;
        } else {
            m_r = -__builtin_inff();
            l_r = 0.0f;
        }
    }

    for (int cc = 0; cc < 8; ++cc) {
        const int j0  = hh*128 + cc*16;
        const int par = cc & 1;

        // T prefetch
        float tval[4][4];
#pragma unroll
        for (int r = 0; r < 4; ++r) {
            const int jg = j0 + quad*4 + r;
#pragma unroll
            for (int nt = 0; nt < 4; ++nt)
                tval[nt][r] = T[jg*HH + hcol[nt]];
        }

        // A-frags from Q + P
        short8 afrag[2];
#pragma unroll
        for (int kh = 0; kh < 2; ++kh) {
            const float* qrow = Q + (j0 + l15)*64 + kh*32 + quad*8;
            f32x4 qa = *(const f32x4*)qrow;
            f32x4 qb = *(const f32x4*)(qrow + 4);
            ushort hv[8];
            hv[0] = f2bf(fmaxf(pnA[kh][0] + qa.x, 0.f));
            hv[1] = f2bf(fmaxf(pnA[kh][1] + qa.y, 0.f));
            hv[2] = f2bf(fmaxf(pnA[kh][2] + qa.z, 0.f));
            hv[3] = f2bf(fmaxf(pnA[kh][3] + qa.w, 0.f));
            hv[4] = f2bf(fmaxf(pnA[kh][4] + qb.x, 0.f));
            hv[5] = f2bf(fmaxf(pnA[kh][5] + qb.y, 0.f));
            hv[6] = f2bf(fmaxf(pnA[kh][6] + qb.z, 0.f));
            hv[7] = f2bf(fmaxf(pnA[kh][7] + qb.w, 0.f));
            afrag[kh] = *(short8*)hv;
        }

        f32x4 acc[4];
#pragma unroll
        for (int nt = 0; nt < 4; ++nt) {
            f32x4 a4 = (f32x4){0.f,0.f,0.f,0.f};
            a4 = __builtin_amdgcn_mfma_f32_16x16x32_bf16(afrag[0], bfrag[nt][0], a4, 0, 0, 0);
            a4 = __builtin_amdgcn_mfma_f32_16x16x32_bf16(afrag[1], bfrag[nt][1], a4, 0, 0, 0);
            acc[nt] = a4;
        }

        // gate epilogue (T resident, diag from regs)
        float vals[4][4];
#pragma unroll
        for (int r = 0; r < 4; ++r) {
            const int jg = j0 + quad*4 + r;
            const bool diag = (jg == n);
#pragma unroll
            for (int nt = 0; nt < 4; ++nt) {
                float u = acc[nt][r] + bgv[nt];
                float g = 1.0f / (1.0f + __expf(-u));
                vals[nt][r] = diag ? gval[nt] : g * tval[nt][r];
            }
        }

        // score partials
#pragma unroll
        for (int z = 0; z < 4; ++z) {
            float pp[4];
#pragma unroll
            for (int r = 0; r < 4; ++r) {
                float s = 0.f;
#pragma unroll
                for (int nt = 0; nt < 4; ++nt)
                    s = fmaf(vals[nt][r], wa_reg[z][nt], s);
                pp[r] = red16(s);
            }
            if (l15 == z) {
#pragma unroll
                for (int r = 0; r < 4; ++r)
                    part[par][z][quad*4 + r][wid] = pp[r];
            }
        }
        __syncthreads();   // only barrier per chunk

        // redundant lane-parallel softmax
        float scl0, scl1, scl2, scl3;
        {
            f32x4 pr = *(const f32x4*)&part[par][zg][jj][0];
            float s = cz_r + ((pr.x + pr.y) + (pr.z + pr.w));
            float e = s > 0.f ? s : 0.2f * s;
            float mx = red16max(e);
            float m_new = fmaxf(m_r, mx);
            float at = __expf(e - m_new);
            float ss = red16(at);
            float scale = __expf(m_r - m_new);
            l_r = l_r * scale + ss;
            m_r = m_new;
            alpha_w[wid][jj][zg] = at;
            scl0 = __shfl(scale, 0);
            scl1 = __shfl(scale, 16);
            scl2 = __shfl(scale, 32);
            scl3 = __shfl(scale, 48);
        }
#pragma unroll
        for (int nt = 0; nt < 4; ++nt) {
            vacc[0][nt] *= scl0; vacc[1][nt] *= scl1;
            vacc[2][nt] *= scl2; vacc[3][nt] *= scl3;
        }
#pragma unroll
        for (int r = 0; r < 4; ++r) {
            f32x4 al = *(const f32x4*)&alpha_w[wid][quad*4 + r][0];
#pragma unroll
            for (int nt = 0; nt < 4; ++nt) {
                float v = vals[nt][r];
                vacc[0][nt] = fmaf(al.x, v, vacc[0][nt]);
                vacc[1][nt] = fmaf(al.y, v, vacc[1][nt]);
                vacc[2][nt] = fmaf(al.z, v, vacc[2][nt]);
                vacc[3][nt] = fmaf(al.w, v, vacc[3][nt]);
            }
        }
    }

    // cross-quad reduce, write PV + ML
#pragma unroll
    for (int z = 0; z < 4; ++z)
#pragma unroll
        for (int nt = 0; nt < 4; ++nt)
            vred[quad*4 + z][hcol[nt]] = vacc[z][nt];
    __syncthreads();
#pragma unroll
    for (int z = 0; z < 4; ++z) {
        float s = (vred[0*4+z][t] + vred[1*4+z][t]) + (vred[2*4+z][t] + vred[3*4+z][t]);
        PV[((size_t)(hh*4 + z)*NN + n)*HH + t] = s;
    }
    if (wid == 0 && l15 == 0) {
        ML[((hh*4 + zg)*NN + n)*2 + 0] = m_r;
        ML[((hh*4 + zg)*NN + n)*2 + 1] = l_r;
    }
}

// grid 64: (16 n-tiles) x (4 f-tiles). Fused merge + split-bf16 MFMA projection.
__global__ __launch_bounds__(256) void gat_out_kernel(
    const float* __restrict__ bias, const float* __restrict__ ws,
    float* __restrict__ out)
{
    const int n0 = (blockIdx.x >> 2) * 16;
    const int f0 = (blockIdx.x & 3) * 64;
    const int t    = threadIdx.x;
    const int wid  = t >> 6;
    const int lane = t & 63;
    const int quad = lane >> 4;
    const int l15  = lane & 15;

    const float* PV = ws + WS_PV;
    const float* ML = ws + WS_ML;
    const ushort* W2hi = (const ushort*)(ws + WS_W2H);
    const ushort* W2lo = (const ushort*)(ws + WS_W2L);

    __shared__ __align__(16) float redc[12288/4];        // [3][4][16][16]
    __shared__ __align__(16) float sq[16][4][2];

    // merge scales: t = n_i*8 + z*2 + q (t < 128); q-pairs adjacent lanes
    if (t < 128) {
        const int n_i = t >> 3, z = (t >> 1) & 3, q = t & 1;
        float m = ML[((q*4 + z)*NN + n0 + n_i)*2 + 0];
        float l = ML[((q*4 + z)*NN + n0 + n_i)*2 + 1];
        float mm = fmaxf(m, __shfl_xor(m, 1));
        float s  = __expf(m - mm);
        float ls = l * s;
        ls += __shfl_xor(ls, 1);
        sq[n_i][z][q] = s / ls;
    }
    __syncthreads();

    // wave wid owns z=wid (k stripe [wid*256, +256)); A-frags built in registers
    f32x4 acc[4];
#pragma unroll
    for (int nt = 0; nt < 4; ++nt) acc[nt] = (f32x4){0.f,0.f,0.f,0.f};

    const float s0 = sq[l15][wid][0];
    const float s1 = sq[l15][wid][1];
    const float* pv0 = PV + ((size_t)(0*4 + wid)*NN + n0 + l15)*HH;
    const float* pv1 = PV + ((size_t)(1*4 + wid)*NN + n0 + l15)*HH;

    for (int ks = 0; ks < 8; ++ks) {
        const int kp = ks*32 + quad*8;
        f32x4 p0a = *(const f32x4*)(pv0 + kp);
        f32x4 p0b = *(const f32x4*)(pv0 + kp + 4);
        f32x4 p1a = *(const f32x4*)(pv1 + kp);
        f32x4 p1b = *(const f32x4*)(pv1 + kp + 4);
        float v[8];
        v[0] = s0*p0a.x + s1*p1a.x; v[1] = s0*p0a.y + s1*p1a.y;
        v[2] = s0*p0a.z + s1*p1a.z; v[3] = s0*p0a.w + s1*p1a.w;
        v[4] = s0*p0b.x + s1*p1b.x; v[5] = s0*p0b.y + s1*p1b.y;
        v[6] = s0*p0b.z + s1*p1b.z; v[7] = s0*p0b.w + s1*p1b.w;
        ushort hi[8], lo[8];
#pragma unroll
        for (int c = 0; c < 8; ++c) {
            hi[c] = f2bf(v[c]);
            lo[c] = f2bf(v[c] - bf2f(hi[c]));
        }
        short8 ah = *(short8*)hi;
        short8 al = *(short8*)lo;
        const int kg = wid*256 + kp;
#pragma unroll
        for (int nt = 0; nt < 4; ++nt) {
            const size_t boff = (size_t)(f0 + nt*16 + l15)*1024 + kg;
            short8 bh = *(const short8*)(W2hi + boff);
            short8 bl = *(const short8*)(W2lo + boff);
            acc[nt] = __builtin_amdgcn_mfma_f32_16x16x32_bf16(ah, bh, acc[nt], 0, 0, 0);
            acc[nt] = __builtin_amdgcn_mfma_f32_16x16x32_bf16(ah, bl, acc[nt], 0, 0, 0);
            acc[nt] = __builtin_amdgcn_mfma_f32_16x16x32_bf16(al, bh, acc[nt], 0, 0, 0);
        }
    }
    __syncthreads();

    if (wid > 0) {
#pragma unroll
        for (int nt = 0; nt < 4; ++nt)
#pragma unroll
            for (int r = 0; r < 4; ++r)
                redc[(((wid-1)*4 + nt)*16 + quad*4 + r)*16 + l15] = acc[nt][r];
    }
    __syncthreads();
    if (wid == 0) {
#pragma unroll
        for (int nt = 0; nt < 4; ++nt) {
            const int f = f0 + nt*16 + l15;
            float bv = bias[f];
#pragma unroll
            for (int r = 0; r < 4; ++r) {
                const int row = quad*4 + r;
                float s = acc[nt][r]
                        + redc[((0*4 + nt)*16 + row)*16 + l15]
                        + redc[((1*4 + nt)*16 + row)*16 + l15]
                        + redc[((2*4 + nt)*16 + row)*16 + l15];
                out[(size_t)(n0 + row)*HH + f] = fmaxf(0.25f * s, 0.f) + bv;
            }
        }
    }
}

extern "C" void kernel_launch(void* const* d_in, const int* in_sizes, int n_in,
                              void* d_out, int out_size, void* d_ws, size_t ws_size,
                              hipStream_t stream)
{
    const float* ahs    = (const float*)d_in[0];
    const float* ghs    = (const float*)d_in[1];
    const float* goal   = (const float*)d_in[2];
    const float* action = (const float*)d_in[3];
    const float* Wd     = (const float*)d_in[4];
    const float* b_dist = (const float*)d_in[5];
    const float* Wg     = (const float*)d_in[6];
    const float* b_gate = (const float*)d_in[7];
    const float* w      = (const float*)d_in[8];
    const float* a      = (const float*)d_in[9];
    const float* bias   = (const float*)d_in[10];
    float* ws   = (float*)d_ws;     // needs 3,596,288 bytes
    float* outp = (float*)d_out;

    precompute_kernel<<<272, 256, 0, stream>>>(ahs, goal, action, Wd, b_dist, Wg, w, a, ws);
    gat_partial_kernel<<<512, 256, 0, stream>>>(ahs, ghs, b_gate, ws);
    gat_out_kernel<<<64, 256, 0, stream>>>(bias, ws, outp);
}